// Round 7
// baseline (591.693 us; speedup 1.0000x reference)
//
#include <hip/hip_runtime.h>
#include <cstdint>

typedef __attribute__((ext_vector_type(8))) short bf16x8;
typedef __attribute__((ext_vector_type(4))) float f32x4;
typedef unsigned short u16;

#define RD(p) (*(const bf16x8*)(p))

__device__ inline u16 f2bf(float f) {
  union { float f; unsigned int u; } v; v.f = f;
  unsigned int u = v.u;
  unsigned int r = (u + 0x7fffu + ((u >> 16) & 1u)) >> 16;
  return (u16)r;
}

__device__ inline void gload_lds16(const u16* g, u16* l) {
  __builtin_amdgcn_global_load_lds(
      (const __attribute__((address_space(1))) void*)g,
      (__attribute__((address_space(3))) void*)l, 16, 0, 0);
}

#define PH_BEGIN() \
  __builtin_amdgcn_s_barrier(); \
  asm volatile("s_waitcnt lgkmcnt(0)" ::: "memory"); \
  __builtin_amdgcn_s_setprio(1)
#define PH_END() \
  __builtin_amdgcn_s_setprio(0); \
  __builtin_amdgcn_s_barrier()

// ---- conversions ----
__global__ void cvt_f32_bf16(const float* __restrict__ src, u16* __restrict__ dst, int n8) {
  int i = blockIdx.x * blockDim.x + threadIdx.x;
  int stride = gridDim.x * blockDim.x;
  for (; i < n8; i += stride) {
    const float4* s = (const float4*)(src + (size_t)i * 8);
    float4 a = s[0], b = s[1];
    union { u16 h[8]; uint4 v; } o;
    o.h[0] = f2bf(a.x); o.h[1] = f2bf(a.y); o.h[2] = f2bf(a.z); o.h[3] = f2bf(a.w);
    o.h[4] = f2bf(b.x); o.h[5] = f2bf(b.y); o.h[6] = f2bf(b.z); o.h[7] = f2bf(b.w);
    *(uint4*)(dst + (size_t)i * 8) = o.v;
  }
}

// merged weight conversion: 3 equal-size segments (w1, w3, w2), 524288 groups each
__global__ void cvt_w3x(const float* __restrict__ s0, const float* __restrict__ s1,
                        const float* __restrict__ s2, u16* __restrict__ d0,
                        u16* __restrict__ d1, u16* __restrict__ d2) {
  const int n8 = 524288;  // 4194304 / 8
  int i = blockIdx.x * blockDim.x + threadIdx.x;
  int stride = gridDim.x * blockDim.x;
  for (; i < 3 * n8; i += stride) {
    int seg = i / n8;
    int j = i - seg * n8;
    const float* src = (seg == 0) ? s0 : (seg == 1) ? s1 : s2;
    u16* dst = (seg == 0) ? d0 : (seg == 1) ? d1 : d2;
    const float4* s = (const float4*)(src + (size_t)j * 8);
    float4 a = s[0], b = s[1];
    union { u16 h[8]; uint4 v; } o;
    o.h[0] = f2bf(a.x); o.h[1] = f2bf(a.y); o.h[2] = f2bf(a.z); o.h[3] = f2bf(a.w);
    o.h[4] = f2bf(b.x); o.h[5] = f2bf(b.y); o.h[6] = f2bf(b.z); o.h[7] = f2bf(b.w);
    *(uint4*)(dst + (size_t)j * 8) = o.v;
  }
}

// ==================== fused gate+up, 8-phase 256x128 tile ====================
// Swapped-operand MFMA: mfma(b, a) => lane holds token = frag*16 + (ln&15),
// 4 regs = 4 consecutive ff columns -> packed 8B nt-stores.
__launch_bounds__(512, 2)
__global__ void gemm_gateup8(const u16* __restrict__ xb, const u16* __restrict__ w1b,
                             const u16* __restrict__ w3b, u16* __restrict__ hout) {
  constexpr int NT = 8;  // K = 512 / 64
  __shared__ __attribute__((aligned(16))) u16 lA[2][256 * 64];      // 32768 B / buf
  __shared__ __attribute__((aligned(16))) u16 lB[2][2][128 * 64];   // [buf][mat]

  int bid = blockIdx.x;
  int sw = (bid & 7) * 512 + (bid >> 3);   // bijective, 4096 % 8 == 0
  int nblk = sw >> 10;
  int rem = sw & 1023;
  int mt = rem >> 4, nt = rem & 15;

  int tid = threadIdx.x, w = tid >> 6, ln = tid & 63;
  int wr = w >> 1, wc = w & 1;
  int l15 = ln & 15, l4 = ln >> 4;
  int lr = ln >> 3, ln8 = ln & 7;

  // read offsets (bytes); 3-bit XOR swizzle
  int cx0 = ((l4 ^ (l15 & 7)) << 4);
  int cx1 = (((4 + l4) ^ (l15 & 7)) << 4);
  int aOff0 = (wr * 64 + l15) * 128 + cx0;
  int aOff1 = (wr * 64 + l15) * 128 + cx1;
  int bOff0 = (wc * 64 + l15) * 128 + cx0;
  int bOff1 = (wc * 64 + l15) * 128 + cx1;

  // stage constants
  int u0t = w * 8, u1t = 64 + w * 8;
  int rbA0 = ((u0t >> 5) << 6) + (u0t & 31);
  int rbA1 = ((u1t >> 5) << 6) + (u1t & 31);
  int dA0 = rbA0 * 128, dA1 = rbA1 * 128;
  int dB0 = u0t * 128, dB1 = u1t * 128;
  int gaA0 = rbA0 * 2048, gaA1 = rbA1 * 2048;
  int gaB0 = u0t * 512, gaB1 = u1t * 512;
  int swzg = (ln8 ^ lr) << 3;

  const u16* gA  = xb  + (size_t)(mt * 256) * 2048 + nblk * 512 + lr * 2048 + swzg;
  const u16* gB1 = w1b + (size_t)nblk * (2048 * 512) + (size_t)(nt * 128) * 512 + lr * 512 + swzg;
  const u16* gB3 = w3b + (size_t)nblk * (2048 * 512) + (size_t)(nt * 128) * 512 + lr * 512 + swzg;

  f32x4 acc1[4][4], acc3[4][4];
#pragma unroll
  for (int i = 0; i < 4; i++)
#pragma unroll
    for (int j = 0; j < 4; j++) {
      acc1[i][j] = (f32x4){0.f, 0.f, 0.f, 0.f};
      acc3[i][j] = (f32x4){0.f, 0.f, 0.f, 0.f};
    }

  // prologue: t0.{Alo,B3,Ahi,B1}, t1.{Alo,B3,Ahi}
  gload_lds16(gA + gaA0,          (u16*)((char*)lA + dA0));
  gload_lds16(gA + gaA1,          (u16*)((char*)lA + dA1));
  gload_lds16(gB3 + gaB0,         (u16*)((char*)lB + 16384 + dB0));
  gload_lds16(gB3 + gaB1,         (u16*)((char*)lB + 16384 + dB1));
  gload_lds16(gA + gaA0 + 65536,  (u16*)((char*)lA + dA0 + 4096));
  gload_lds16(gA + gaA1 + 65536,  (u16*)((char*)lA + dA1 + 4096));
  gload_lds16(gB1 + gaB0,         (u16*)((char*)lB + dB0));
  gload_lds16(gB1 + gaB1,         (u16*)((char*)lB + dB1));
  gload_lds16(gA + 64 + gaA0,         (u16*)((char*)lA + 32768 + dA0));
  gload_lds16(gA + 64 + gaA1,         (u16*)((char*)lA + 32768 + dA1));
  gload_lds16(gB3 + 64 + gaB0,        (u16*)((char*)lB + 32768 + 16384 + dB0));
  gload_lds16(gB3 + 64 + gaB1,        (u16*)((char*)lB + 32768 + 16384 + dB1));
  gload_lds16(gA + 64 + gaA0 + 65536, (u16*)((char*)lA + 32768 + dA0 + 4096));
  gload_lds16(gA + 64 + gaA1 + 65536, (u16*)((char*)lA + 32768 + dA1 + 4096));
  gA += 128; gB3 += 128; gB1 += 64;
  asm volatile("s_waitcnt vmcnt(6)" ::: "memory");
  __builtin_amdgcn_s_barrier();

  int sCur = 0, sNxt = 32768;
  bf16x8 aT[2][2], aH[2][2], b1[4][2], b3[4][2];

  for (int kt = 0; kt < NT; ++kt) {
    const char* pA0 = (const char*)lA + (sCur + aOff0);
    const char* pA1 = (const char*)lA + (sCur + aOff1);
    const char* pB0 = (const char*)lB + (sCur + bOff0);
    const char* pB1p = (const char*)lB + (sCur + bOff1);
    bool s1 = (kt + 1 < NT), s2 = (kt + 2 < NT);

    // ---- P0: read A-lo + B1; stage t+1.B1 (other buf)
#pragma unroll
    for (int f = 0; f < 2; ++f) {
      aT[f][0] = RD(pA0 + f * 2048); aT[f][1] = RD(pA1 + f * 2048);
    }
#pragma unroll
    for (int g = 0; g < 4; ++g) {
      b1[g][0] = RD(pB0 + g * 2048); b1[g][1] = RD(pB1p + g * 2048);
    }
    if (s1) {
      gload_lds16(gB1 + gaB0, (u16*)((char*)lB + sNxt + dB0));
      gload_lds16(gB1 + gaB1, (u16*)((char*)lB + sNxt + dB1));
    }
    asm volatile("s_waitcnt lgkmcnt(8)" ::: "memory");
    PH_BEGIN();
#pragma unroll
    for (int f = 0; f < 2; ++f)
#pragma unroll
      for (int g = 0; g < 4; ++g)
#pragma unroll
        for (int ks = 0; ks < 2; ++ks)
          acc1[f][g] = __builtin_amdgcn_mfma_f32_16x16x32_bf16(b1[g][ks], aT[f][ks], acc1[f][g], 0, 0, 0);
    PH_END();

    // ---- P1: read B3; stage t+2.A-lo (cur buf)
#pragma unroll
    for (int g = 0; g < 4; ++g) {
      b3[g][0] = RD(pB0 + 16384 + g * 2048); b3[g][1] = RD(pB1p + 16384 + g * 2048);
    }
    if (s2) {
      gload_lds16(gA + gaA0, (u16*)((char*)lA + sCur + dA0));
      gload_lds16(gA + gaA1, (u16*)((char*)lA + sCur + dA1));
    }
    PH_BEGIN();
#pragma unroll
    for (int f = 0; f < 2; ++f)
#pragma unroll
      for (int g = 0; g < 4; ++g)
#pragma unroll
        for (int ks = 0; ks < 2; ++ks)
          acc3[f][g] = __builtin_amdgcn_mfma_f32_16x16x32_bf16(b3[g][ks], aT[f][ks], acc3[f][g], 0, 0, 0);
    PH_END();

    // ---- P2: read A-hi; stage t+2.B3 (cur buf)
#pragma unroll
    for (int f = 0; f < 2; ++f) {
      aH[f][0] = RD(pA0 + 4096 + f * 2048); aH[f][1] = RD(pA1 + 4096 + f * 2048);
    }
    if (s2) {
      gload_lds16(gB3 + gaB0, (u16*)((char*)lB + sCur + 16384 + dB0));
      gload_lds16(gB3 + gaB1, (u16*)((char*)lB + sCur + 16384 + dB1));
    }
    PH_BEGIN();
#pragma unroll
    for (int f = 0; f < 2; ++f)
#pragma unroll
      for (int g = 0; g < 4; ++g)
#pragma unroll
        for (int ks = 0; ks < 2; ++ks)
          acc1[2 + f][g] = __builtin_amdgcn_mfma_f32_16x16x32_bf16(b1[g][ks], aH[f][ks], acc1[2 + f][g], 0, 0, 0);
    PH_END();

    // ---- P3: stage t+2.A-hi (cur buf); trailing counted vmcnt
    if (s2) {
      gload_lds16(gA + gaA0 + 65536, (u16*)((char*)lA + sCur + dA0 + 4096));
      gload_lds16(gA + gaA1 + 65536, (u16*)((char*)lA + sCur + dA1 + 4096));
    }
    PH_BEGIN();
#pragma unroll
    for (int f = 0; f < 2; ++f)
#pragma unroll
      for (int g = 0; g < 4; ++g)
#pragma unroll
        for (int ks = 0; ks < 2; ++ks)
          acc3[2 + f][g] = __builtin_amdgcn_mfma_f32_16x16x32_bf16(b3[g][ks], aH[f][ks], acc3[2 + f][g], 0, 0, 0);
    __builtin_amdgcn_s_setprio(0);
    if (kt < NT - 2)       asm volatile("s_waitcnt vmcnt(6)" ::: "memory");
    else if (kt == NT - 2) asm volatile("s_waitcnt vmcnt(0)" ::: "memory");
    __builtin_amdgcn_s_barrier();
    gA += 64; gB1 += 64; gB3 += 64;
    sCur ^= 32768; sNxt ^= 32768;
  }

  // epilogue: swapped layout — token = f*16 + l15, ff = g*16 + l4*4 + r
  // nt-stores: avoid write-allocate HBM fetch + L2 pollution
  u16* Hb = hout + (size_t)(mt * 256 + wr * 64) * 8192 + nblk * 2048 + nt * 128 + wc * 64;
#pragma unroll
  for (int f = 0; f < 4; ++f) {
    u16* Hrow = Hb + (size_t)(f * 16 + l15) * 8192 + l4 * 4;
#pragma unroll
    for (int g = 0; g < 4; ++g) {
      union { u16 h[4]; unsigned long long v; } o;
#pragma unroll
      for (int r = 0; r < 4; ++r) {
        float gate = acc1[f][g][r];
        float up = acc3[f][g][r];
        float s = gate * __builtin_amdgcn_rcpf(1.f + __expf(-gate));
        o.h[r] = f2bf(s * up);
      }
      __builtin_nontemporal_store(o.v, (unsigned long long*)(Hrow + g * 16));
    }
  }
}

// ==================== down projection, 8-phase 256x256 tile ====================
__launch_bounds__(512, 2)
__global__ void gemm_down8(const u16* __restrict__ hmat, const u16* __restrict__ w2b,
                           float* __restrict__ out) {
  constexpr int NT = 32;  // K = 2048 / 64
  __shared__ __attribute__((aligned(16))) u16 lA[2][256 * 64];
  __shared__ __attribute__((aligned(16))) u16 lB[2][256 * 64];

  int bid = blockIdx.x;
  int sw = (bid & 7) * 64 + (bid >> 3);   // 512 wg, bijective
  int nblk = sw >> 7;
  int rem = sw & 127;
  int mt = rem >> 1, nt = rem & 1;

  int tid = threadIdx.x, w = tid >> 6, ln = tid & 63;
  int mi = w >> 2, nj = w & 3;
  int l15 = ln & 15, l4 = ln >> 4;
  int lr = ln >> 3, ln8 = ln & 7;

  int cx0 = ((l4 ^ (l15 & 7)) << 4);
  int cx1 = (((4 + l4) ^ (l15 & 7)) << 4);
  int aOff0 = (mi * 128 + l15) * 128 + cx0;
  int aOff1 = (mi * 128 + l15) * 128 + cx1;
  int bOff0 = (nj * 64 + l15) * 128 + cx0;
  int bOff1 = (nj * 64 + l15) * 128 + cx1;

  int u0t = w * 8, u1t = 64 + w * 8;
  int dA0 = u0t * 128, dA1 = (64 + u1t) * 128;
  int rbB0 = ((u0t >> 5) << 6) + (u0t & 31);
  int rbB1 = ((u1t >> 5) << 6) + (u1t & 31);
  int dB0 = rbB0 * 128, dB1 = rbB1 * 128;
  int gaA0 = u0t * 8192, gaA1 = (64 + u1t) * 8192;
  int gaB0 = rbB0 * 2048, gaB1 = rbB1 * 2048;
  int swzg = (ln8 ^ lr) << 3;

  const u16* gA = hmat + (size_t)(mt * 256) * 8192 + nblk * 2048 + lr * 8192 + swzg;
  const u16* gB = w2b + (size_t)nblk * (512 * 2048) + (size_t)(nt * 256) * 2048 + lr * 2048 + swzg;

  f32x4 acc[8][4];
#pragma unroll
  for (int i = 0; i < 8; i++)
#pragma unroll
    for (int j = 0; j < 4; j++) acc[i][j] = (f32x4){0.f, 0.f, 0.f, 0.f};

  // prologue: t0.{Alo,Bhi,Ahi,Blo}, t1.{Alo,Bhi,Ahi}
  gload_lds16(gA + gaA0,           (u16*)((char*)lA + dA0));
  gload_lds16(gA + gaA1,           (u16*)((char*)lA + dA1));
  gload_lds16(gB + gaB0 + 65536,   (u16*)((char*)lB + dB0 + 4096));
  gload_lds16(gB + gaB1 + 65536,   (u16*)((char*)lB + dB1 + 4096));
  gload_lds16(gA + gaA0 + 524288,  (u16*)((char*)lA + dA0 + 8192));
  gload_lds16(gA + gaA1 + 524288,  (u16*)((char*)lA + dA1 + 8192));
  gload_lds16(gB + gaB0,           (u16*)((char*)lB + dB0));
  gload_lds16(gB + gaB1,           (u16*)((char*)lB + dB1));
  gload_lds16(gA + 64 + gaA0,          (u16*)((char*)lA + 32768 + dA0));
  gload_lds16(gA + 64 + gaA1,          (u16*)((char*)lA + 32768 + dA1));
  gload_lds16(gB + 64 + gaB0 + 65536,  (u16*)((char*)lB + 32768 + dB0 + 4096));
  gload_lds16(gB + 64 + gaB1 + 65536,  (u16*)((char*)lB + 32768 + dB1 + 4096));
  gload_lds16(gA + 64 + gaA0 + 524288, (u16*)((char*)lA + 32768 + dA0 + 8192));
  gload_lds16(gA + 64 + gaA1 + 524288, (u16*)((char*)lA + 32768 + dA1 + 8192));
  gA += 128; gB += 64;   // gA at t2; gB at t1 (Blo t+1, Bhi t+2 via +64)
  asm volatile("s_waitcnt vmcnt(6)" ::: "memory");
  __builtin_amdgcn_s_barrier();

  int sCur = 0, sNxt = 32768;
  bf16x8 aF[4][2], bLo[2][2], bHi[2][2];

  for (int kt = 0; kt < NT; ++kt) {
    const char* pA0 = (const char*)lA + (sCur + aOff0);
    const char* pA1 = (const char*)lA + (sCur + aOff1);
    const char* pB0 = (const char*)lB + (sCur + bOff0);
    const char* pB1p = (const char*)lB + (sCur + bOff1);
    bool s1 = (kt + 1 < NT), s2 = (kt + 2 < NT);

    // ---- P0: read A f0-3 + B-lo; stage t+1.B-lo (other buf)
#pragma unroll
    for (int f = 0; f < 4; ++f) {
      aF[f][0] = RD(pA0 + f * 2048); aF[f][1] = RD(pA1 + f * 2048);
    }
#pragma unroll
    for (int g = 0; g < 2; ++g) {
      bLo[g][0] = RD(pB0 + g * 2048); bLo[g][1] = RD(pB1p + g * 2048);
    }
    if (s1) {
      gload_lds16(gB + gaB0, (u16*)((char*)lB + sNxt + dB0));
      gload_lds16(gB + gaB1, (u16*)((char*)lB + sNxt + dB1));
    }
    asm volatile("s_waitcnt lgkmcnt(8)" ::: "memory");
    PH_BEGIN();
#pragma unroll
    for (int f = 0; f < 4; ++f)
#pragma unroll
      for (int g = 0; g < 2; ++g)
#pragma unroll
        for (int ks = 0; ks < 2; ++ks)
          acc[f][g] = __builtin_amdgcn_mfma_f32_16x16x32_bf16(bLo[g][ks], aF[f][ks], acc[f][g], 0, 0, 0);
    PH_END();

    // ---- P1: read B-hi; stage t+2.A-lo (cur buf)
#pragma unroll
    for (int g = 0; g < 2; ++g) {
      bHi[g][0] = RD(pB0 + 4096 + g * 2048); bHi[g][1] = RD(pB1p + 4096 + g * 2048);
    }
    if (s2) {
      gload_lds16(gA + gaA0, (u16*)((char*)lA + sCur + dA0));
      gload_lds16(gA + gaA1, (u16*)((char*)lA + sCur + dA1));
    }
    PH_BEGIN();
#pragma unroll
    for (int f = 0; f < 4; ++f)
#pragma unroll
      for (int g = 0; g < 2; ++g)
#pragma unroll
        for (int ks = 0; ks < 2; ++ks)
          acc[f][2 + g] = __builtin_amdgcn_mfma_f32_16x16x32_bf16(bHi[g][ks], aF[f][ks], acc[f][2 + g], 0, 0, 0);
    PH_END();

    // ---- P2: read A f4-7; stage t+2.B-hi (cur buf)
#pragma unroll
    for (int f = 0; f < 4; ++f) {
      aF[f][0] = RD(pA0 + 8192 + f * 2048); aF[f][1] = RD(pA1 + 8192 + f * 2048);
    }
    if (s2) {
      gload_lds16(gB + 64 + gaB0 + 65536, (u16*)((char*)lB + sCur + dB0 + 4096));
      gload_lds16(gB + 64 + gaB1 + 65536, (u16*)((char*)lB + sCur + dB1 + 4096));
    }
    PH_BEGIN();
#pragma unroll
    for (int f = 0; f < 4; ++f)
#pragma unroll
      for (int g = 0; g < 2; ++g)
#pragma unroll
        for (int ks = 0; ks < 2; ++ks)
          acc[4 + f][g] = __builtin_amdgcn_mfma_f32_16x16x32_bf16(bLo[g][ks], aF[f][ks], acc[4 + f][g], 0, 0, 0);
    PH_END();

    // ---- P3: stage t+2.A-hi (cur buf); trailing counted vmcnt
    if (s2) {
      gload_lds16(gA + gaA0 + 524288, (u16*)((char*)lA + sCur + dA0 + 8192));
      gload_lds16(gA + gaA1 + 524288, (u16*)((char*)lA + sCur + dA1 + 8192));
    }
    PH_BEGIN();
#pragma unroll
    for (int f = 0; f < 4; ++f)
#pragma unroll
      for (int g = 0; g < 2; ++g)
#pragma unroll
        for (int ks = 0; ks < 2; ++ks)
          acc[4 + f][2 + g] = __builtin_amdgcn_mfma_f32_16x16x32_bf16(bHi[g][ks], aF[f][ks], acc[4 + f][2 + g], 0, 0, 0);
    __builtin_amdgcn_s_setprio(0);
    if (kt < NT - 2)       asm volatile("s_waitcnt vmcnt(6)" ::: "memory");
    else if (kt == NT - 2) asm volatile("s_waitcnt vmcnt(0)" ::: "memory");
    __builtin_amdgcn_s_barrier();
    gA += 64; gB += 64;
    sCur ^= 32768; sNxt ^= 32768;
  }

  // epilogue: swapped layout — token = f*16 + l15, d = g*16 + l4*4 + r; nt 16B stores
  float* Ob = out + (size_t)(mt * 256 + mi * 128) * 2048 + nblk * 512 + nt * 256 + nj * 64;
#pragma unroll
  for (int f = 0; f < 8; ++f) {
    float* Orow = Ob + (size_t)(f * 16 + l15) * 2048 + l4 * 4;
#pragma unroll
    for (int g = 0; g < 4; ++g)
      __builtin_nontemporal_store(acc[f][g], (f32x4*)(Orow + g * 16));
  }
}

extern "C" void kernel_launch(void* const* d_in, const int* in_sizes, int n_in,
                              void* d_out, int out_size, void* d_ws, size_t ws_size,
                              hipStream_t stream) {
  const float* x  = (const float*)d_in[0];
  const float* w1 = (const float*)d_in[1];
  const float* w3 = (const float*)d_in[2];
  const float* w2 = (const float*)d_in[3];

  char* ws = (char*)d_ws;
  u16* xb  = (u16*)(ws);                 // 64 MiB
  u16* w1b = (u16*)(ws + 67108864);      // 8 MiB
  u16* w3b = (u16*)(ws + 75497472);
  u16* w2b = (u16*)(ws + 83886080);
  u16* h   = (u16*)(ws + 92274688);      // 256 MiB

  cvt_w3x<<<2048, 256, 0, stream>>>(w1, w3, w2, w1b, w3b, w2b);
  cvt_f32_bf16<<<2048, 256, 0, stream>>>(x, xb, 33554432 / 8);

  gemm_gateup8<<<4096, 512, 0, stream>>>(xb, w1b, w3b, h);
  gemm_down8<<<512, 512, 0, stream>>>(h, w2b, (float*)d_out);
}

// Round 8
// 569.012 us; speedup vs baseline: 1.0399x; 1.0399x over previous
//
#include <hip/hip_runtime.h>
#include <cstdint>

typedef __attribute__((ext_vector_type(8))) short bf16x8;
typedef __attribute__((ext_vector_type(4))) float f32x4;
typedef unsigned short u16;

#define RD(p) (*(const bf16x8*)(p))

__device__ inline u16 f2bf(float f) {
  union { float f; unsigned int u; } v; v.f = f;
  unsigned int u = v.u;
  unsigned int r = (u + 0x7fffu + ((u >> 16) & 1u)) >> 16;
  return (u16)r;
}

__device__ inline void gload_lds16(const u16* g, u16* l) {
  __builtin_amdgcn_global_load_lds(
      (const __attribute__((address_space(1))) void*)g,
      (__attribute__((address_space(3))) void*)l, 16, 0, 0);
}

#define PH_BEGIN() \
  __builtin_amdgcn_s_barrier(); \
  asm volatile("s_waitcnt lgkmcnt(0)" ::: "memory"); \
  __builtin_amdgcn_s_setprio(1)
#define PH_END() \
  __builtin_amdgcn_s_setprio(0); \
  __builtin_amdgcn_s_barrier()

// ---- conversions ----
__global__ void cvt_f32_bf16(const float* __restrict__ src, u16* __restrict__ dst, int n8) {
  int i = blockIdx.x * blockDim.x + threadIdx.x;
  int stride = gridDim.x * blockDim.x;
  for (; i < n8; i += stride) {
    const float4* s = (const float4*)(src + (size_t)i * 8);
    float4 a = s[0], b = s[1];
    union { u16 h[8]; uint4 v; } o;
    o.h[0] = f2bf(a.x); o.h[1] = f2bf(a.y); o.h[2] = f2bf(a.z); o.h[3] = f2bf(a.w);
    o.h[4] = f2bf(b.x); o.h[5] = f2bf(b.y); o.h[6] = f2bf(b.z); o.h[7] = f2bf(b.w);
    *(uint4*)(dst + (size_t)i * 8) = o.v;
  }
}

__global__ void cvt_w3x(const float* __restrict__ s0, const float* __restrict__ s1,
                        const float* __restrict__ s2, u16* __restrict__ d0,
                        u16* __restrict__ d1, u16* __restrict__ d2) {
  const int n8 = 524288;  // 4194304 / 8
  int i = blockIdx.x * blockDim.x + threadIdx.x;
  int stride = gridDim.x * blockDim.x;
  for (; i < 3 * n8; i += stride) {
    int seg = i / n8;
    int j = i - seg * n8;
    const float* src = (seg == 0) ? s0 : (seg == 1) ? s1 : s2;
    u16* dst = (seg == 0) ? d0 : (seg == 1) ? d1 : d2;
    const float4* s = (const float4*)(src + (size_t)j * 8);
    float4 a = s[0], b = s[1];
    union { u16 h[8]; uint4 v; } o;
    o.h[0] = f2bf(a.x); o.h[1] = f2bf(a.y); o.h[2] = f2bf(a.z); o.h[3] = f2bf(a.w);
    o.h[4] = f2bf(b.x); o.h[5] = f2bf(b.y); o.h[6] = f2bf(b.z); o.h[7] = f2bf(b.w);
    *(uint4*)(dst + (size_t)j * 8) = o.v;
  }
}

// ==================== fused gate+up, 8-phase 256x128 tile, TPB=4, swapped MFMA ====================
__launch_bounds__(512, 2)
__global__ void gemm_gateup8(const u16* __restrict__ xb, const u16* __restrict__ w1b,
                             const u16* __restrict__ w3b, u16* __restrict__ hout) {
  constexpr int NT = 8;          // K-tiles per output tile (K=512)
  constexpr int TPB = 4;         // output tiles per block (nt dir, shared A panel)
  constexpr int TOT = NT * TPB;  // 32 flat K-steps
  __shared__ __attribute__((aligned(16))) u16 lA[2][256 * 64];
  __shared__ __attribute__((aligned(16))) u16 lB[2][2][128 * 64];

  int bid = blockIdx.x;
  int sw = (bid & 7) * 128 + (bid >> 3);   // 1024 wg, bijective
  int nblk = sw >> 8;
  int rem = sw & 255;
  int mt = rem >> 2, ntg = rem & 3;        // nt = ntg*4 + tile

  int tid = threadIdx.x, w = tid >> 6, ln = tid & 63;
  int wr = w >> 1, wc = w & 1;
  int l15 = ln & 15, l4 = ln >> 4;
  int lr = ln >> 3, ln8 = ln & 7;

  // read offsets (bytes); 3-bit XOR swizzle
  int cx0 = ((l4 ^ (l15 & 7)) << 4);
  int cx1 = (((4 + l4) ^ (l15 & 7)) << 4);
  int aOff0 = (wr * 64 + l15) * 128 + cx0;
  int aOff1 = (wr * 64 + l15) * 128 + cx1;
  int bOff0 = (wc * 64 + l15) * 128 + cx0;
  int bOff1 = (wc * 64 + l15) * 128 + cx1;

  // stage constants
  int u0t = w * 8, u1t = 64 + w * 8;
  int rbA0 = ((u0t >> 5) << 6) + (u0t & 31);
  int rbA1 = ((u1t >> 5) << 6) + (u1t & 31);
  int dA0 = rbA0 * 128, dA1 = rbA1 * 128;
  int dB0 = u0t * 128, dB1 = u1t * 128;
  int gaA0 = rbA0 * 2048, gaA1 = rbA1 * 2048;
  int gaB0 = u0t * 512, gaB1 = u1t * 512;
  int swzg = (ln8 ^ lr) << 3;

  const u16* gA  = xb  + (size_t)(mt * 256) * 2048 + nblk * 512 + lr * 2048 + swzg;
  const u16* gB1 = w1b + (size_t)nblk * (2048 * 512) + (size_t)(ntg * 512) * 512 + lr * 512 + swzg;
  const u16* gB3 = w3b + (size_t)nblk * (2048 * 512) + (size_t)(ntg * 512) * 512 + lr * 512 + swzg;

  // stage source offsets vs flat step s: A same panel (k wraps); B jumps 128 rows/tile
  #define OFFA(s) (((s) & 7) * 64)
  #define OFFB(s) ((((s) >> 3) << 16) + (((s) & 7) * 64))

  f32x4 acc1[4][4], acc3[4][4];
#pragma unroll
  for (int i = 0; i < 4; i++)
#pragma unroll
    for (int j = 0; j < 4; j++) {
      acc1[i][j] = (f32x4){0.f, 0.f, 0.f, 0.f};
      acc3[i][j] = (f32x4){0.f, 0.f, 0.f, 0.f};
    }

  // prologue: s=0 {Alo,B3,Ahi,B1} -> buf0, s=1 {Alo,B3,Ahi} -> buf1
  gload_lds16(gA + gaA0,              (u16*)((char*)lA + dA0));
  gload_lds16(gA + gaA1,              (u16*)((char*)lA + dA1));
  gload_lds16(gB3 + gaB0,             (u16*)((char*)lB + 16384 + dB0));
  gload_lds16(gB3 + gaB1,             (u16*)((char*)lB + 16384 + dB1));
  gload_lds16(gA + gaA0 + 65536,      (u16*)((char*)lA + dA0 + 4096));
  gload_lds16(gA + gaA1 + 65536,      (u16*)((char*)lA + dA1 + 4096));
  gload_lds16(gB1 + gaB0,             (u16*)((char*)lB + dB0));
  gload_lds16(gB1 + gaB1,             (u16*)((char*)lB + dB1));
  gload_lds16(gA + OFFA(1) + gaA0,          (u16*)((char*)lA + 32768 + dA0));
  gload_lds16(gA + OFFA(1) + gaA1,          (u16*)((char*)lA + 32768 + dA1));
  gload_lds16(gB3 + OFFB(1) + gaB0,         (u16*)((char*)lB + 32768 + 16384 + dB0));
  gload_lds16(gB3 + OFFB(1) + gaB1,         (u16*)((char*)lB + 32768 + 16384 + dB1));
  gload_lds16(gA + OFFA(1) + gaA0 + 65536,  (u16*)((char*)lA + 32768 + dA0 + 4096));
  gload_lds16(gA + OFFA(1) + gaA1 + 65536,  (u16*)((char*)lA + 32768 + dA1 + 4096));
  asm volatile("s_waitcnt vmcnt(6)" ::: "memory");
  __builtin_amdgcn_s_barrier();

  int sCur = 0, sNxt = 32768;
  bf16x8 aT[2][2], aH[2][2], b1[4][2], b3[4][2];

  for (int kt = 0; kt < TOT; ++kt) {
    const char* pA0 = (const char*)lA + (sCur + aOff0);
    const char* pA1 = (const char*)lA + (sCur + aOff1);
    const char* pB0 = (const char*)lB + (sCur + bOff0);
    const char* pB1p = (const char*)lB + (sCur + bOff1);
    int s1 = kt + 1, s2 = kt + 2;
    int oA2 = OFFA(s2), oB1n = OFFB(s1), oB32 = OFFB(s2);
    bool q1 = (s1 < TOT), q2 = (s2 < TOT);

    // ---- P0: read A-lo + B1; stage B1 @ s+1 (other buf)
#pragma unroll
    for (int f = 0; f < 2; ++f) {
      aT[f][0] = RD(pA0 + f * 2048); aT[f][1] = RD(pA1 + f * 2048);
    }
#pragma unroll
    for (int g = 0; g < 4; ++g) {
      b1[g][0] = RD(pB0 + g * 2048); b1[g][1] = RD(pB1p + g * 2048);
    }
    if (q1) {
      gload_lds16(gB1 + oB1n + gaB0, (u16*)((char*)lB + sNxt + dB0));
      gload_lds16(gB1 + oB1n + gaB1, (u16*)((char*)lB + sNxt + dB1));
    }
    asm volatile("s_waitcnt lgkmcnt(8)" ::: "memory");
    PH_BEGIN();
#pragma unroll
    for (int f = 0; f < 2; ++f)
#pragma unroll
      for (int g = 0; g < 4; ++g)
#pragma unroll
        for (int ks = 0; ks < 2; ++ks)
          acc1[f][g] = __builtin_amdgcn_mfma_f32_16x16x32_bf16(b1[g][ks], aT[f][ks], acc1[f][g], 0, 0, 0);
    PH_END();

    // ---- P1: read B3; stage A-lo @ s+2 (cur buf)
#pragma unroll
    for (int g = 0; g < 4; ++g) {
      b3[g][0] = RD(pB0 + 16384 + g * 2048); b3[g][1] = RD(pB1p + 16384 + g * 2048);
    }
    if (q2) {
      gload_lds16(gA + oA2 + gaA0, (u16*)((char*)lA + sCur + dA0));
      gload_lds16(gA + oA2 + gaA1, (u16*)((char*)lA + sCur + dA1));
    }
    PH_BEGIN();
#pragma unroll
    for (int f = 0; f < 2; ++f)
#pragma unroll
      for (int g = 0; g < 4; ++g)
#pragma unroll
        for (int ks = 0; ks < 2; ++ks)
          acc3[f][g] = __builtin_amdgcn_mfma_f32_16x16x32_bf16(b3[g][ks], aT[f][ks], acc3[f][g], 0, 0, 0);
    PH_END();

    // ---- P2: read A-hi; stage B3 @ s+2 (cur buf)
#pragma unroll
    for (int f = 0; f < 2; ++f) {
      aH[f][0] = RD(pA0 + 4096 + f * 2048); aH[f][1] = RD(pA1 + 4096 + f * 2048);
    }
    if (q2) {
      gload_lds16(gB3 + oB32 + gaB0, (u16*)((char*)lB + sCur + 16384 + dB0));
      gload_lds16(gB3 + oB32 + gaB1, (u16*)((char*)lB + sCur + 16384 + dB1));
    }
    PH_BEGIN();
#pragma unroll
    for (int f = 0; f < 2; ++f)
#pragma unroll
      for (int g = 0; g < 4; ++g)
#pragma unroll
        for (int ks = 0; ks < 2; ++ks)
          acc1[2 + f][g] = __builtin_amdgcn_mfma_f32_16x16x32_bf16(b1[g][ks], aH[f][ks], acc1[2 + f][g], 0, 0, 0);
    PH_END();

    // ---- P3: stage A-hi @ s+2 (cur buf); trailing counted vmcnt
    if (q2) {
      gload_lds16(gA + oA2 + gaA0 + 65536, (u16*)((char*)lA + sCur + dA0 + 4096));
      gload_lds16(gA + oA2 + gaA1 + 65536, (u16*)((char*)lA + sCur + dA1 + 4096));
    }
    PH_BEGIN();
#pragma unroll
    for (int f = 0; f < 2; ++f)
#pragma unroll
      for (int g = 0; g < 4; ++g)
#pragma unroll
        for (int ks = 0; ks < 2; ++ks)
          acc3[2 + f][g] = __builtin_amdgcn_mfma_f32_16x16x32_bf16(b3[g][ks], aH[f][ks], acc3[2 + f][g], 0, 0, 0);
    __builtin_amdgcn_s_setprio(0);
    if (kt < TOT - 2)       asm volatile("s_waitcnt vmcnt(6)" ::: "memory");
    else if (kt == TOT - 2) asm volatile("s_waitcnt vmcnt(0)" ::: "memory");
    __builtin_amdgcn_s_barrier();
    sCur ^= 32768; sNxt ^= 32768;

    // ---- per-tile epilogue: tight burst of packed 8B stores (full-line completion),
    // issued AFTER the counted vmcnt so stores get a full K-step to retire.
    if ((kt & 7) == 7) {
      int nt = ntg * 4 + (kt >> 3);
      u16* Hb = hout + (size_t)(mt * 256 + wr * 64) * 8192 + nblk * 2048 + nt * 128 + wc * 64;
#pragma unroll
      for (int f = 0; f < 4; ++f) {
        u16* Hrow = Hb + (size_t)(f * 16 + l15) * 8192 + l4 * 4;
#pragma unroll
        for (int g = 0; g < 4; ++g) {
          union { u16 h[4]; uint2 v; } o;
#pragma unroll
          for (int r = 0; r < 4; ++r) {
            float gate = acc1[f][g][r];
            float up = acc3[f][g][r];
            float s = gate * __builtin_amdgcn_rcpf(1.f + __expf(-gate));
            o.h[r] = f2bf(s * up);
          }
          *(uint2*)(Hrow + g * 16) = o.v;
        }
      }
#pragma unroll
      for (int i = 0; i < 4; i++)
#pragma unroll
        for (int j = 0; j < 4; j++) {
          acc1[i][j] = (f32x4){0.f, 0.f, 0.f, 0.f};
          acc3[i][j] = (f32x4){0.f, 0.f, 0.f, 0.f};
        }
    }
  }
  #undef OFFA
  #undef OFFB
}

// ==================== down projection, 8-phase 256x256 tile, swapped MFMA ====================
__launch_bounds__(512, 2)
__global__ void gemm_down8(const u16* __restrict__ hmat, const u16* __restrict__ w2b,
                           float* __restrict__ out) {
  constexpr int NT = 32;  // K = 2048 / 64
  __shared__ __attribute__((aligned(16))) u16 lA[2][256 * 64];
  __shared__ __attribute__((aligned(16))) u16 lB[2][256 * 64];

  int bid = blockIdx.x;
  int sw = (bid & 7) * 64 + (bid >> 3);   // 512 wg, bijective
  int nblk = sw >> 7;
  int rem = sw & 127;
  int mt = rem >> 1, nt = rem & 1;

  int tid = threadIdx.x, w = tid >> 6, ln = tid & 63;
  int mi = w >> 2, nj = w & 3;
  int l15 = ln & 15, l4 = ln >> 4;
  int lr = ln >> 3, ln8 = ln & 7;

  int cx0 = ((l4 ^ (l15 & 7)) << 4);
  int cx1 = (((4 + l4) ^ (l15 & 7)) << 4);
  int aOff0 = (mi * 128 + l15) * 128 + cx0;
  int aOff1 = (mi * 128 + l15) * 128 + cx1;
  int bOff0 = (nj * 64 + l15) * 128 + cx0;
  int bOff1 = (nj * 64 + l15) * 128 + cx1;

  int u0t = w * 8, u1t = 64 + w * 8;
  int dA0 = u0t * 128, dA1 = (64 + u1t) * 128;
  int rbB0 = ((u0t >> 5) << 6) + (u0t & 31);
  int rbB1 = ((u1t >> 5) << 6) + (u1t & 31);
  int dB0 = rbB0 * 128, dB1 = rbB1 * 128;
  int gaA0 = u0t * 8192, gaA1 = (64 + u1t) * 8192;
  int gaB0 = rbB0 * 2048, gaB1 = rbB1 * 2048;
  int swzg = (ln8 ^ lr) << 3;

  const u16* gA = hmat + (size_t)(mt * 256) * 8192 + nblk * 2048 + lr * 8192 + swzg;
  const u16* gB = w2b + (size_t)nblk * (512 * 2048) + (size_t)(nt * 256) * 2048 + lr * 2048 + swzg;

  f32x4 acc[8][4];
#pragma unroll
  for (int i = 0; i < 8; i++)
#pragma unroll
    for (int j = 0; j < 4; j++) acc[i][j] = (f32x4){0.f, 0.f, 0.f, 0.f};

  // prologue: t0.{Alo,Bhi,Ahi,Blo}, t1.{Alo,Bhi,Ahi}
  gload_lds16(gA + gaA0,           (u16*)((char*)lA + dA0));
  gload_lds16(gA + gaA1,           (u16*)((char*)lA + dA1));
  gload_lds16(gB + gaB0 + 65536,   (u16*)((char*)lB + dB0 + 4096));
  gload_lds16(gB + gaB1 + 65536,   (u16*)((char*)lB + dB1 + 4096));
  gload_lds16(gA + gaA0 + 524288,  (u16*)((char*)lA + dA0 + 8192));
  gload_lds16(gA + gaA1 + 524288,  (u16*)((char*)lA + dA1 + 8192));
  gload_lds16(gB + gaB0,           (u16*)((char*)lB + dB0));
  gload_lds16(gB + gaB1,           (u16*)((char*)lB + dB1));
  gload_lds16(gA + 64 + gaA0,          (u16*)((char*)lA + 32768 + dA0));
  gload_lds16(gA + 64 + gaA1,          (u16*)((char*)lA + 32768 + dA1));
  gload_lds16(gB + 64 + gaB0 + 65536,  (u16*)((char*)lB + 32768 + dB0 + 4096));
  gload_lds16(gB + 64 + gaB1 + 65536,  (u16*)((char*)lB + 32768 + dB1 + 4096));
  gload_lds16(gA + 64 + gaA0 + 524288, (u16*)((char*)lA + 32768 + dA0 + 8192));
  gload_lds16(gA + 64 + gaA1 + 524288, (u16*)((char*)lA + 32768 + dA1 + 8192));
  gA += 128; gB += 64;   // gA at t2; gB at t1 (Blo t+1, Bhi t+2 via +64)
  asm volatile("s_waitcnt vmcnt(6)" ::: "memory");
  __builtin_amdgcn_s_barrier();

  int sCur = 0, sNxt = 32768;
  bf16x8 aF[4][2], bLo[2][2], bHi[2][2];

  for (int kt = 0; kt < NT; ++kt) {
    const char* pA0 = (const char*)lA + (sCur + aOff0);
    const char* pA1 = (const char*)lA + (sCur + aOff1);
    const char* pB0 = (const char*)lB + (sCur + bOff0);
    const char* pB1p = (const char*)lB + (sCur + bOff1);
    bool s1 = (kt + 1 < NT), s2 = (kt + 2 < NT);

    // ---- P0: read A f0-3 + B-lo; stage t+1.B-lo (other buf)
#pragma unroll
    for (int f = 0; f < 4; ++f) {
      aF[f][0] = RD(pA0 + f * 2048); aF[f][1] = RD(pA1 + f * 2048);
    }
#pragma unroll
    for (int g = 0; g < 2; ++g) {
      bLo[g][0] = RD(pB0 + g * 2048); bLo[g][1] = RD(pB1p + g * 2048);
    }
    if (s1) {
      gload_lds16(gB + gaB0, (u16*)((char*)lB + sNxt + dB0));
      gload_lds16(gB + gaB1, (u16*)((char*)lB + sNxt + dB1));
    }
    asm volatile("s_waitcnt lgkmcnt(8)" ::: "memory");
    PH_BEGIN();
#pragma unroll
    for (int f = 0; f < 4; ++f)
#pragma unroll
      for (int g = 0; g < 2; ++g)
#pragma unroll
        for (int ks = 0; ks < 2; ++ks)
          acc[f][g] = __builtin_amdgcn_mfma_f32_16x16x32_bf16(bLo[g][ks], aF[f][ks], acc[f][g], 0, 0, 0);
    PH_END();

    // ---- P1: read B-hi; stage t+2.A-lo (cur buf)
#pragma unroll
    for (int g = 0; g < 2; ++g) {
      bHi[g][0] = RD(pB0 + 4096 + g * 2048); bHi[g][1] = RD(pB1p + 4096 + g * 2048);
    }
    if (s2) {
      gload_lds16(gA + gaA0, (u16*)((char*)lA + sCur + dA0));
      gload_lds16(gA + gaA1, (u16*)((char*)lA + sCur + dA1));
    }
    PH_BEGIN();
#pragma unroll
    for (int f = 0; f < 4; ++f)
#pragma unroll
      for (int g = 0; g < 2; ++g)
#pragma unroll
        for (int ks = 0; ks < 2; ++ks)
          acc[f][2 + g] = __builtin_amdgcn_mfma_f32_16x16x32_bf16(bHi[g][ks], aF[f][ks], acc[f][2 + g], 0, 0, 0);
    PH_END();

    // ---- P2: read A f4-7; stage t+2.B-hi (cur buf)
#pragma unroll
    for (int f = 0; f < 4; ++f) {
      aF[f][0] = RD(pA0 + 8192 + f * 2048); aF[f][1] = RD(pA1 + 8192 + f * 2048);
    }
    if (s2) {
      gload_lds16(gB + 64 + gaB0 + 65536, (u16*)((char*)lB + sCur + dB0 + 4096));
      gload_lds16(gB + 64 + gaB1 + 65536, (u16*)((char*)lB + sCur + dB1 + 4096));
    }
    PH_BEGIN();
#pragma unroll
    for (int f = 0; f < 4; ++f)
#pragma unroll
      for (int g = 0; g < 2; ++g)
#pragma unroll
        for (int ks = 0; ks < 2; ++ks)
          acc[4 + f][g] = __builtin_amdgcn_mfma_f32_16x16x32_bf16(bLo[g][ks], aF[f][ks], acc[4 + f][g], 0, 0, 0);
    PH_END();

    // ---- P3: stage t+2.A-hi (cur buf); trailing counted vmcnt
    if (s2) {
      gload_lds16(gA + gaA0 + 524288, (u16*)((char*)lA + sCur + dA0 + 8192));
      gload_lds16(gA + gaA1 + 524288, (u16*)((char*)lA + sCur + dA1 + 8192));
    }
    PH_BEGIN();
#pragma unroll
    for (int f = 0; f < 4; ++f)
#pragma unroll
      for (int g = 0; g < 2; ++g)
#pragma unroll
        for (int ks = 0; ks < 2; ++ks)
          acc[4 + f][2 + g] = __builtin_amdgcn_mfma_f32_16x16x32_bf16(bHi[g][ks], aF[f][ks], acc[4 + f][2 + g], 0, 0, 0);
    __builtin_amdgcn_s_setprio(0);
    if (kt < NT - 2)       asm volatile("s_waitcnt vmcnt(6)" ::: "memory");
    else if (kt == NT - 2) asm volatile("s_waitcnt vmcnt(0)" ::: "memory");
    __builtin_amdgcn_s_barrier();
    gA += 64; gB += 64;
    sCur ^= 32768; sNxt ^= 32768;
  }

  // epilogue: swapped layout — token = f*16 + l15, d = g*16 + l4*4 + r; plain 16B stores
  float* Ob = out + (size_t)(mt * 256 + mi * 128) * 2048 + nblk * 512 + nt * 256 + nj * 64;
#pragma unroll
  for (int f = 0; f < 8; ++f) {
    float* Orow = Ob + (size_t)(f * 16 + l15) * 2048 + l4 * 4;
#pragma unroll
    for (int g = 0; g < 4; ++g)
      *(f32x4*)(Orow + g * 16) = acc[f][g];
  }
}

extern "C" void kernel_launch(void* const* d_in, const int* in_sizes, int n_in,
                              void* d_out, int out_size, void* d_ws, size_t ws_size,
                              hipStream_t stream) {
  const float* x  = (const float*)d_in[0];
  const float* w1 = (const float*)d_in[1];
  const float* w3 = (const float*)d_in[2];
  const float* w2 = (const float*)d_in[3];

  char* ws = (char*)d_ws;
  u16* xb  = (u16*)(ws);                 // 64 MiB
  u16* w1b = (u16*)(ws + 67108864);      // 8 MiB
  u16* w3b = (u16*)(ws + 75497472);
  u16* w2b = (u16*)(ws + 83886080);
  u16* h   = (u16*)(ws + 92274688);      // 256 MiB

  cvt_w3x<<<2048, 256, 0, stream>>>(w1, w3, w2, w1b, w3b, w2b);
  cvt_f32_bf16<<<2048, 256, 0, stream>>>(x, xb, 33554432 / 8);

  gemm_gateup8<<<1024, 512, 0, stream>>>(xb, w1b, w3b, h);
  gemm_down8<<<512, 512, 0, stream>>>(h, w2b, (float*)d_out);
}

// Round 9
// 482.927 us; speedup vs baseline: 1.2252x; 1.1783x over previous
//
#include <hip/hip_runtime.h>
#include <cstdint>

typedef __attribute__((ext_vector_type(8))) short bf16x8;
typedef __attribute__((ext_vector_type(4))) float f32x4;
typedef unsigned short u16;

#define RD(p) (*(const bf16x8*)(p))

__device__ inline u16 f2bf(float f) {
  union { float f; unsigned int u; } v; v.f = f;
  unsigned int u = v.u;
  unsigned int r = (u + 0x7fffu + ((u >> 16) & 1u)) >> 16;
  return (u16)r;
}

__device__ inline void gload_lds16(const u16* g, u16* l) {
  __builtin_amdgcn_global_load_lds(
      (const __attribute__((address_space(1))) void*)g,
      (__attribute__((address_space(3))) void*)l, 16, 0, 0);
}

#define PH_BEGIN() \
  __builtin_amdgcn_s_barrier(); \
  asm volatile("s_waitcnt lgkmcnt(0)" ::: "memory"); \
  __builtin_amdgcn_s_setprio(1)
#define PH_END() \
  __builtin_amdgcn_s_setprio(0); \
  __builtin_amdgcn_s_barrier()

// ---- conversions ----
__global__ void cvt_f32_bf16(const float* __restrict__ src, u16* __restrict__ dst, int n8) {
  int i = blockIdx.x * blockDim.x + threadIdx.x;
  int stride = gridDim.x * blockDim.x;
  for (; i < n8; i += stride) {
    const float4* s = (const float4*)(src + (size_t)i * 8);
    float4 a = s[0], b = s[1];
    union { u16 h[8]; uint4 v; } o;
    o.h[0] = f2bf(a.x); o.h[1] = f2bf(a.y); o.h[2] = f2bf(a.z); o.h[3] = f2bf(a.w);
    o.h[4] = f2bf(b.x); o.h[5] = f2bf(b.y); o.h[6] = f2bf(b.z); o.h[7] = f2bf(b.w);
    *(uint4*)(dst + (size_t)i * 8) = o.v;
  }
}

__global__ void cvt_w3x(const float* __restrict__ s0, const float* __restrict__ s1,
                        const float* __restrict__ s2, u16* __restrict__ d0,
                        u16* __restrict__ d1, u16* __restrict__ d2) {
  const int n8 = 524288;
  int i = blockIdx.x * blockDim.x + threadIdx.x;
  int stride = gridDim.x * blockDim.x;
  for (; i < 3 * n8; i += stride) {
    int seg = i / n8;
    int j = i - seg * n8;
    const float* src = (seg == 0) ? s0 : (seg == 1) ? s1 : s2;
    u16* dst = (seg == 0) ? d0 : (seg == 1) ? d1 : d2;
    const float4* s = (const float4*)(src + (size_t)j * 8);
    float4 a = s[0], b = s[1];
    union { u16 h[8]; uint4 v; } o;
    o.h[0] = f2bf(a.x); o.h[1] = f2bf(a.y); o.h[2] = f2bf(a.z); o.h[3] = f2bf(a.w);
    o.h[4] = f2bf(b.x); o.h[5] = f2bf(b.y); o.h[6] = f2bf(b.z); o.h[7] = f2bf(b.w);
    *(uint4*)(dst + (size_t)j * 8) = o.v;
  }
}

// ==================== fused gate+up, 2-phase 256x128 tile, TPB=4, swapped MFMA ====================
__launch_bounds__(512, 2)
__global__ void gemm_gateup2(const u16* __restrict__ xb, const u16* __restrict__ w1b,
                             const u16* __restrict__ w3b, u16* __restrict__ hout) {
  constexpr int NT = 8;          // K-tiles per output tile (K=512)
  constexpr int TPB = 4;         // output tiles per block (nt dir, shared A panel)
  constexpr int TOT = NT * TPB;  // 32 flat K-steps
  __shared__ __attribute__((aligned(16))) u16 lA[2][256 * 64];
  __shared__ __attribute__((aligned(16))) u16 lB[2][2][128 * 64];

  int bid = blockIdx.x;
  int sw = (bid & 7) * 128 + (bid >> 3);   // 1024 wg, bijective
  int nblk = sw >> 8;
  int rem = sw & 255;
  int mt = rem >> 2, ntg = rem & 3;

  int tid = threadIdx.x, w = tid >> 6, ln = tid & 63;
  int wr = w >> 1, wc = w & 1;
  int l15 = ln & 15, l4 = ln >> 4;
  int lr = ln >> 3, ln8 = ln & 7;

  // read offsets (bytes); 3-bit XOR swizzle
  int cx0 = ((l4 ^ (l15 & 7)) << 4);
  int cx1 = (((4 + l4) ^ (l15 & 7)) << 4);
  int aOff0 = (wr * 64 + l15) * 128 + cx0;
  int aOff1 = (wr * 64 + l15) * 128 + cx1;
  int bOff0 = (wc * 64 + l15) * 128 + cx0;
  int bOff1 = (wc * 64 + l15) * 128 + cx1;

  // stage constants
  int u0t = w * 8, u1t = 64 + w * 8;
  int rbA0 = ((u0t >> 5) << 6) + (u0t & 31);
  int rbA1 = ((u1t >> 5) << 6) + (u1t & 31);
  int dA0 = rbA0 * 128, dA1 = rbA1 * 128;
  int dB0 = u0t * 128, dB1 = u1t * 128;
  int gaA0 = rbA0 * 2048, gaA1 = rbA1 * 2048;
  int gaB0 = u0t * 512, gaB1 = u1t * 512;
  int swzg = (ln8 ^ lr) << 3;

  const u16* gA  = xb  + (size_t)(mt * 256) * 2048 + nblk * 512 + lr * 2048 + swzg;
  const u16* gB1 = w1b + (size_t)nblk * (2048 * 512) + (size_t)(ntg * 512) * 512 + lr * 512 + swzg;
  const u16* gB3 = w3b + (size_t)nblk * (2048 * 512) + (size_t)(ntg * 512) * 512 + lr * 512 + swzg;

  #define OFFA(s) (((s) & 7) * 64)
  #define OFFB(s) ((((s) >> 3) << 16) + (((s) & 7) * 64))

  f32x4 acc1[4][4], acc3[4][4];
#pragma unroll
  for (int i = 0; i < 4; i++)
#pragma unroll
    for (int j = 0; j < 4; j++) {
      acc1[i][j] = (f32x4){0.f, 0.f, 0.f, 0.f};
      acc3[i][j] = (f32x4){0.f, 0.f, 0.f, 0.f};
    }

  // prologue: s0 full (A x4, B1 x2, B3 x2) -> buf0; A@1 x4 -> buf1
  gload_lds16(gA + gaA0,          (u16*)((char*)lA + dA0));
  gload_lds16(gA + gaA1,          (u16*)((char*)lA + dA1));
  gload_lds16(gA + gaA0 + 65536,  (u16*)((char*)lA + dA0 + 4096));
  gload_lds16(gA + gaA1 + 65536,  (u16*)((char*)lA + dA1 + 4096));
  gload_lds16(gB1 + gaB0,         (u16*)((char*)lB + dB0));
  gload_lds16(gB1 + gaB1,         (u16*)((char*)lB + dB1));
  gload_lds16(gB3 + gaB0,         (u16*)((char*)lB + 16384 + dB0));
  gload_lds16(gB3 + gaB1,         (u16*)((char*)lB + 16384 + dB1));
  gload_lds16(gA + OFFA(1) + gaA0,         (u16*)((char*)lA + 32768 + dA0));
  gload_lds16(gA + OFFA(1) + gaA1,         (u16*)((char*)lA + 32768 + dA1));
  gload_lds16(gA + OFFA(1) + gaA0 + 65536, (u16*)((char*)lA + 32768 + dA0 + 4096));
  gload_lds16(gA + OFFA(1) + gaA1 + 65536, (u16*)((char*)lA + 32768 + dA1 + 4096));
  asm volatile("s_waitcnt vmcnt(4)" ::: "memory");
  __builtin_amdgcn_s_barrier();

  int sCur = 0, sNxt = 32768;
  bf16x8 aT[4][2], bb[4][2];

  for (int kt = 0; kt < TOT; ++kt) {
    const char* pA0 = (const char*)lA + (sCur + aOff0);
    const char* pA1 = (const char*)lA + (sCur + aOff1);
    const char* pB0 = (const char*)lB + (sCur + bOff0);
    const char* pB1p = (const char*)lB + (sCur + bOff1);
    int s1 = kt + 1, s2 = kt + 2;
    int oA2 = OFFA(s2), oBn = OFFB(s1);
    bool q1 = (s1 < TOT), q2 = (s2 < TOT);

    // ---- P0: read full A (8) + B1 (8); stage B1@s+1 + B3@s+1 (other buf)
#pragma unroll
    for (int f = 0; f < 2; ++f) {
      aT[f][0] = RD(pA0 + f * 2048);        aT[f][1] = RD(pA1 + f * 2048);
      aT[2 + f][0] = RD(pA0 + 4096 + f * 2048); aT[2 + f][1] = RD(pA1 + 4096 + f * 2048);
    }
#pragma unroll
    for (int g = 0; g < 4; ++g) {
      bb[g][0] = RD(pB0 + g * 2048); bb[g][1] = RD(pB1p + g * 2048);
    }
    if (q1) {
      gload_lds16(gB1 + oBn + gaB0, (u16*)((char*)lB + sNxt + dB0));
      gload_lds16(gB1 + oBn + gaB1, (u16*)((char*)lB + sNxt + dB1));
      gload_lds16(gB3 + oBn + gaB0, (u16*)((char*)lB + sNxt + 16384 + dB0));
      gload_lds16(gB3 + oBn + gaB1, (u16*)((char*)lB + sNxt + 16384 + dB1));
    }
    PH_BEGIN();
#pragma unroll
    for (int f = 0; f < 4; ++f)
#pragma unroll
      for (int g = 0; g < 4; ++g)
#pragma unroll
        for (int ks = 0; ks < 2; ++ks)
          acc1[f][g] = __builtin_amdgcn_mfma_f32_16x16x32_bf16(bb[g][ks], aT[f][ks], acc1[f][g], 0, 0, 0);
    PH_END();

    // ---- P1: read B3 (8); stage A@s+2 (cur buf, strictly after P0's A reads)
#pragma unroll
    for (int g = 0; g < 4; ++g) {
      bb[g][0] = RD(pB0 + 16384 + g * 2048); bb[g][1] = RD(pB1p + 16384 + g * 2048);
    }
    if (q2) {
      gload_lds16(gA + oA2 + gaA0,         (u16*)((char*)lA + sCur + dA0));
      gload_lds16(gA + oA2 + gaA1,         (u16*)((char*)lA + sCur + dA1));
      gload_lds16(gA + oA2 + gaA0 + 65536, (u16*)((char*)lA + sCur + dA0 + 4096));
      gload_lds16(gA + oA2 + gaA1 + 65536, (u16*)((char*)lA + sCur + dA1 + 4096));
    }
    PH_BEGIN();
#pragma unroll
    for (int f = 0; f < 4; ++f)
#pragma unroll
      for (int g = 0; g < 4; ++g)
#pragma unroll
        for (int ks = 0; ks < 2; ++ks)
          acc3[f][g] = __builtin_amdgcn_mfma_f32_16x16x32_bf16(bb[g][ks], aT[f][ks], acc3[f][g], 0, 0, 0);
    __builtin_amdgcn_s_setprio(0);
    if (kt < TOT - 2)       asm volatile("s_waitcnt vmcnt(4)" ::: "memory");
    else if (kt == TOT - 2) asm volatile("s_waitcnt vmcnt(0)" ::: "memory");
    __builtin_amdgcn_s_barrier();
    sCur ^= 32768; sNxt ^= 32768;

    // ---- per-tile epilogue (burst of packed 8B stores)
    if ((kt & 7) == 7) {
      int nt = ntg * 4 + (kt >> 3);
      u16* Hb = hout + (size_t)(mt * 256 + wr * 64) * 8192 + nblk * 2048 + nt * 128 + wc * 64;
#pragma unroll
      for (int f = 0; f < 4; ++f) {
        u16* Hrow = Hb + (size_t)(f * 16 + l15) * 8192 + l4 * 4;
#pragma unroll
        for (int g = 0; g < 4; ++g) {
          union { u16 h[4]; uint2 v; } o;
#pragma unroll
          for (int r = 0; r < 4; ++r) {
            float gate = acc1[f][g][r];
            float up = acc3[f][g][r];
            float s = gate * __builtin_amdgcn_rcpf(1.f + __expf(-gate));
            o.h[r] = f2bf(s * up);
          }
          *(uint2*)(Hrow + g * 16) = o.v;
        }
      }
#pragma unroll
      for (int i = 0; i < 4; i++)
#pragma unroll
        for (int j = 0; j < 4; j++) {
          acc1[i][j] = (f32x4){0.f, 0.f, 0.f, 0.f};
          acc3[i][j] = (f32x4){0.f, 0.f, 0.f, 0.f};
        }
    }
  }
  #undef OFFA
  #undef OFFB
}

// ==================== down projection, 2-phase 256x256 tile, swapped MFMA ====================
__launch_bounds__(512, 2)
__global__ void gemm_down2(const u16* __restrict__ hmat, const u16* __restrict__ w2b,
                           float* __restrict__ out) {
  constexpr int NT = 32;  // K = 2048 / 64
  __shared__ __attribute__((aligned(16))) u16 lA[2][256 * 64];
  __shared__ __attribute__((aligned(16))) u16 lB[2][256 * 64];

  int bid = blockIdx.x;
  int sw = (bid & 7) * 64 + (bid >> 3);   // 512 wg, bijective
  int nblk = sw >> 7;
  int rem = sw & 127;
  int mt = rem >> 1, nt = rem & 1;

  int tid = threadIdx.x, w = tid >> 6, ln = tid & 63;
  int mi = w >> 2, nj = w & 3;
  int l15 = ln & 15, l4 = ln >> 4;
  int lr = ln >> 3, ln8 = ln & 7;

  int cx0 = ((l4 ^ (l15 & 7)) << 4);
  int cx1 = (((4 + l4) ^ (l15 & 7)) << 4);
  int aOff0 = (mi * 128 + l15) * 128 + cx0;
  int aOff1 = (mi * 128 + l15) * 128 + cx1;
  int bOff0 = (nj * 64 + l15) * 128 + cx0;
  int bOff1 = (nj * 64 + l15) * 128 + cx1;

  int u0t = w * 8, u1t = 64 + w * 8;
  int dA0 = u0t * 128, dA1 = (64 + u1t) * 128;
  int rbB0 = ((u0t >> 5) << 6) + (u0t & 31);
  int rbB1 = ((u1t >> 5) << 6) + (u1t & 31);
  int dB0 = rbB0 * 128, dB1 = rbB1 * 128;
  int gaA0 = u0t * 8192, gaA1 = (64 + u1t) * 8192;
  int gaB0 = rbB0 * 2048, gaB1 = rbB1 * 2048;
  int swzg = (ln8 ^ lr) << 3;

  const u16* gA = hmat + (size_t)(mt * 256) * 8192 + nblk * 2048 + lr * 8192 + swzg;
  const u16* gB = w2b + (size_t)nblk * (512 * 2048) + (size_t)(nt * 256) * 2048 + lr * 2048 + swzg;

  f32x4 acc[8][4];
#pragma unroll
  for (int i = 0; i < 8; i++)
#pragma unroll
    for (int j = 0; j < 4; j++) acc[i][j] = (f32x4){0.f, 0.f, 0.f, 0.f};

  // prologue: s0 full (A x4, B x4) -> buf0; s1: A-f03 x2 + B-hi x2 -> buf1
  gload_lds16(gA + gaA0,            (u16*)((char*)lA + dA0));
  gload_lds16(gA + gaA1,            (u16*)((char*)lA + dA1));
  gload_lds16(gA + gaA0 + 524288,   (u16*)((char*)lA + dA0 + 8192));
  gload_lds16(gA + gaA1 + 524288,   (u16*)((char*)lA + dA1 + 8192));
  gload_lds16(gB + gaB0,            (u16*)((char*)lB + dB0));
  gload_lds16(gB + gaB1,            (u16*)((char*)lB + dB1));
  gload_lds16(gB + gaB0 + 65536,    (u16*)((char*)lB + dB0 + 4096));
  gload_lds16(gB + gaB1 + 65536,    (u16*)((char*)lB + dB1 + 4096));
  gload_lds16(gA + 64 + gaA0,           (u16*)((char*)lA + 32768 + dA0));
  gload_lds16(gA + 64 + gaA1,           (u16*)((char*)lA + 32768 + dA1));
  gload_lds16(gB + 64 + gaB0 + 65536,   (u16*)((char*)lB + 32768 + dB0 + 4096));
  gload_lds16(gB + 64 + gaB1 + 65536,   (u16*)((char*)lB + 32768 + dB1 + 4096));
  asm volatile("s_waitcnt vmcnt(4)" ::: "memory");
  __builtin_amdgcn_s_barrier();

  int sCur = 0, sNxt = 32768;
  bf16x8 aF[4][2], bLo[2][2], bHi[2][2];

  for (int kt = 0; kt < NT; ++kt) {
    const char* pA0 = (const char*)lA + (sCur + aOff0);
    const char* pA1 = (const char*)lA + (sCur + aOff1);
    const char* pB0 = (const char*)lB + (sCur + bOff0);
    const char* pB1p = (const char*)lB + (sCur + bOff1);
    int kO1 = (kt + 1) * 64, kO2 = (kt + 2) * 64;
    bool q1 = (kt + 1 < NT), q2 = (kt + 2 < NT);

    // ---- P0: read A f0-3 (8) + B-lo (4) + B-hi (4); stage B-lo@+1 + A-f47@+1 (other buf)
#pragma unroll
    for (int f = 0; f < 4; ++f) {
      aF[f][0] = RD(pA0 + f * 2048); aF[f][1] = RD(pA1 + f * 2048);
    }
#pragma unroll
    for (int g = 0; g < 2; ++g) {
      bLo[g][0] = RD(pB0 + g * 2048);        bLo[g][1] = RD(pB1p + g * 2048);
      bHi[g][0] = RD(pB0 + 4096 + g * 2048); bHi[g][1] = RD(pB1p + 4096 + g * 2048);
    }
    if (q1) {
      gload_lds16(gB + kO1 + gaB0,          (u16*)((char*)lB + sNxt + dB0));
      gload_lds16(gB + kO1 + gaB1,          (u16*)((char*)lB + sNxt + dB1));
      gload_lds16(gA + kO1 + gaA0 + 524288, (u16*)((char*)lA + sNxt + dA0 + 8192));
      gload_lds16(gA + kO1 + gaA1 + 524288, (u16*)((char*)lA + sNxt + dA1 + 8192));
    }
    PH_BEGIN();
#pragma unroll
    for (int f = 0; f < 4; ++f)
#pragma unroll
      for (int g = 0; g < 2; ++g)
#pragma unroll
        for (int ks = 0; ks < 2; ++ks) {
          acc[f][g]     = __builtin_amdgcn_mfma_f32_16x16x32_bf16(bLo[g][ks], aF[f][ks], acc[f][g], 0, 0, 0);
          acc[f][2 + g] = __builtin_amdgcn_mfma_f32_16x16x32_bf16(bHi[g][ks], aF[f][ks], acc[f][2 + g], 0, 0, 0);
        }
    PH_END();

    // ---- P1: read A f4-7 (8); stage A-f03@+2 + B-hi@+2 (cur buf)
#pragma unroll
    for (int f = 0; f < 4; ++f) {
      aF[f][0] = RD(pA0 + 8192 + f * 2048); aF[f][1] = RD(pA1 + 8192 + f * 2048);
    }
    if (q2) {
      gload_lds16(gA + kO2 + gaA0,         (u16*)((char*)lA + sCur + dA0));
      gload_lds16(gA + kO2 + gaA1,         (u16*)((char*)lA + sCur + dA1));
      gload_lds16(gB + kO2 + gaB0 + 65536, (u16*)((char*)lB + sCur + dB0 + 4096));
      gload_lds16(gB + kO2 + gaB1 + 65536, (u16*)((char*)lB + sCur + dB1 + 4096));
    }
    PH_BEGIN();
#pragma unroll
    for (int f = 0; f < 4; ++f)
#pragma unroll
      for (int g = 0; g < 2; ++g)
#pragma unroll
        for (int ks = 0; ks < 2; ++ks) {
          acc[4 + f][g]     = __builtin_amdgcn_mfma_f32_16x16x32_bf16(bLo[g][ks], aF[f][ks], acc[4 + f][g], 0, 0, 0);
          acc[4 + f][2 + g] = __builtin_amdgcn_mfma_f32_16x16x32_bf16(bHi[g][ks], aF[f][ks], acc[4 + f][2 + g], 0, 0, 0);
        }
    __builtin_amdgcn_s_setprio(0);
    if (kt < NT - 2)       asm volatile("s_waitcnt vmcnt(4)" ::: "memory");
    else if (kt == NT - 2) asm volatile("s_waitcnt vmcnt(0)" ::: "memory");
    __builtin_amdgcn_s_barrier();
    sCur ^= 32768; sNxt ^= 32768;
  }

  // epilogue: swapped layout — token = f*16 + l15, d = g*16 + l4*4 + r; 16B stores
  float* Ob = out + (size_t)(mt * 256 + mi * 128) * 2048 + nblk * 512 + nt * 256 + nj * 64;
#pragma unroll
  for (int f = 0; f < 8; ++f) {
    float* Orow = Ob + (size_t)(f * 16 + l15) * 2048 + l4 * 4;
#pragma unroll
    for (int g = 0; g < 4; ++g)
      *(f32x4*)(Orow + g * 16) = acc[f][g];
  }
}

extern "C" void kernel_launch(void* const* d_in, const int* in_sizes, int n_in,
                              void* d_out, int out_size, void* d_ws, size_t ws_size,
                              hipStream_t stream) {
  const float* x  = (const float*)d_in[0];
  const float* w1 = (const float*)d_in[1];
  const float* w3 = (const float*)d_in[2];
  const float* w2 = (const float*)d_in[3];

  char* ws = (char*)d_ws;
  u16* xb  = (u16*)(ws);                 // 64 MiB
  u16* w1b = (u16*)(ws + 67108864);      // 8 MiB
  u16* w3b = (u16*)(ws + 75497472);
  u16* w2b = (u16*)(ws + 83886080);
  u16* h   = (u16*)(ws + 92274688);      // 256 MiB

  cvt_w3x<<<2048, 256, 0, stream>>>(w1, w3, w2, w1b, w3b, w2b);
  cvt_f32_bf16<<<2048, 256, 0, stream>>>(x, xb, 33554432 / 8);

  gemm_gateup2<<<1024, 512, 0, stream>>>(xb, w1b, w3b, h);
  gemm_down2<<<512, 512, 0, stream>>>(h, w2b, (float*)d_out);
}